// Round 2
// baseline (519.531 us; speedup 1.0000x reference)
//
#include <hip/hip_runtime.h>
#include <cmath>

// Problem constants (B=4, H=12, S=2048, D=64, BLOCK=64, L=32, NUM_STEPS=4)
#define BH_ 48
#define NH_ 12
#define L_  32
#define BS_ 64
#define DD_ 64
#define SS_ 2048

__device__ __forceinline__ float softplus_f(float x) {
    return fmaxf(x, 0.0f) + log1pf(expf(-fabsf(x)));
}

// ---------------------------------------------------------------------------
// Buffer layouts (all float32):
//   lp : [BH][64][32][32]   (j,l,k)          ws
//   rp : [BH][32][64][64]   (k,j,i)          ws
//   LQ : [BH][64][32][64]   (j,k,v)          ws
//   r2 : [BH][64][32]       (j,k)            ws
//   l2 : [BH][32][64]       (k,j)            ws
//   KR : [BH][32][64][64]   (k,j,v)          ALIASED ONTO d_out (also Y)
// KR<->out aliasing is race-free: only kZ reads KR(Y) while writing out, and
// block (bh,j) reads exactly flat rows {((bh*32+r)*64+j)} into LDS before
// writing the same row set; blocks with different j touch disjoint rows.
// ---------------------------------------------------------------------------

// Init kernel: rp := 1/8; KR := column-mean of K (initial right = 1/64
// uniform); r2 := 1/64.   One block per (bh,k).
__global__ __launch_bounds__(256) void kA0(const float* __restrict__ key,
                                           float* __restrict__ rp,
                                           float* __restrict__ KR,
                                           float* __restrict__ r2) {
    int blk = blockIdx.x; int bh = blk >> 5; int k = blk & 31;
    int t = threadIdx.x;
    __shared__ float ms[64];
    float* rpk = rp + ((size_t)(bh * 32 + k)) * 4096;
    for (int idx = t; idx < 4096; idx += 256) rpk[idx] = 0.125f;
    if (t < 64) {
        const float* kbase = key + ((size_t)bh * SS_ + k * 64) * 64 + t;
        float acc = 0.f;
        #pragma unroll
        for (int i = 0; i < 64; ++i) acc += kbase[i * 64];
        ms[t] = acc * (1.0f / 64.0f);
    }
    __syncthreads();
    float* KRk = KR + ((size_t)(bh * 32 + k)) * 4096;
    for (int idx = t; idx < 4096; idx += 256) KRk[idx] = ms[idx & 63];
    if (t < 64) r2[(bh * 64 + t) * 32 + k] = 1.0f / 64.0f;
}

// Left-factor kernel: one block per (bh, j).
// Computes left from lp, t2l from (Q, KR), dl, updates lp, and emits LQ / l2
// from the OLD left (pre-update), as the reference requires.
template <int STEP>
__global__ __launch_bounds__(256) void kB(const float* __restrict__ query,
                                          const float* __restrict__ attn_scale,
                                          const float* __restrict__ step_size,
                                          float* __restrict__ lp,
                                          const float* __restrict__ KR,
                                          const float* __restrict__ r2,
                                          float* __restrict__ LQ,
                                          float* __restrict__ l2) {
    int blk = blockIdx.x; int bh = blk >> 6; int j = blk & 63;
    int h = bh % NH_;
    int t = threadIdx.x;
    __shared__ float Qs[32][65];    // Q[l][v] (scaled)
    __shared__ float KRs[32][65];   // KR[k][v]
    __shared__ float lpS[32][33];   // lp[l][k]
    __shared__ float lsS[32][33];   // ls
    __shared__ float leS[32][33];   // left = ls^2
    __shared__ float dlS[32][33];
    __shared__ float invn[32], r2s[32], rowdot[32];

    float qscale = softplus_f(attn_scale[h]) * 0.125f;   // /sqrt(64)
    float sp0 = softplus_f(step_size[h * 8 + STEP]);     // [h][0][STEP]

    for (int idx = t; idx < 2048; idx += 256) {
        int r = idx >> 6, v = idx & 63;
        Qs[r][v]  = query[((size_t)bh * SS_ + r * 64 + j) * 64 + v] * qscale;
        KRs[r][v] = KR[((size_t)(bh * 32 + r) * 64 + j) * 64 + v];
    }
    float* lpj = lp + ((size_t)(bh * 64 + j)) * 1024;
    for (int idx = t; idx < 1024; idx += 256) {
        int l = idx >> 5, k = idx & 31;
        lpS[l][k] = (STEP == 0) ? 0.17677669529663687f : lpj[idx];
    }
    if (t < 32) r2s[t] = r2[(bh * 64 + j) * 32 + t];
    __syncthreads();

    if (t < 32) {
        float s = 0.f;
        #pragma unroll
        for (int k = 0; k < 32; ++k) { float x = lpS[t][k]; s += x * x; }
        float n = sqrtf(s);
        invn[t] = (n > 0.f) ? 1.0f / n : 0.0f;
    }
    __syncthreads();
    for (int idx = t; idx < 1024; idx += 256) {
        int l = idx >> 5, k = idx & 31;
        float v = lpS[l][k] * invn[l];
        lsS[l][k] = v; leS[l][k] = v * v;
    }
    __syncthreads();

    // t2l[l][k] = sum_v Qs[l][v]*KRs[k][v]; dl1 = 2*ls*(r2[k]*left - t2l)
    {
        int l0 = (t >> 4) * 2, k0 = (t & 15) * 2;
        float a00 = 0, a01 = 0, a10 = 0, a11 = 0;
        #pragma unroll 4
        for (int v = 0; v < 64; ++v) {
            float q0 = Qs[l0][v], q1 = Qs[l0 + 1][v];
            float r0 = KRs[k0][v], r1 = KRs[k0 + 1][v];
            a00 += q0 * r0; a01 += q0 * r1; a10 += q1 * r0; a11 += q1 * r1;
        }
        dlS[l0][k0]         = 2.f * lsS[l0][k0]         * (r2s[k0]     * leS[l0][k0]         - a00);
        dlS[l0][k0 + 1]     = 2.f * lsS[l0][k0 + 1]     * (r2s[k0 + 1] * leS[l0][k0 + 1]     - a01);
        dlS[l0 + 1][k0]     = 2.f * lsS[l0 + 1][k0]     * (r2s[k0]     * leS[l0 + 1][k0]     - a10);
        dlS[l0 + 1][k0 + 1] = 2.f * lsS[l0 + 1][k0 + 1] * (r2s[k0 + 1] * leS[l0 + 1][k0 + 1] - a11);
    }
    __syncthreads();
    if (t < 32) {
        float s = 0.f;
        #pragma unroll
        for (int k = 0; k < 32; ++k) s += lsS[t][k] * dlS[t][k];
        rowdot[t] = s;
    }
    __syncthreads();
    for (int idx = t; idx < 1024; idx += 256) {
        int l = idx >> 5, k = idx & 31;
        float d = (dlS[l][k] - lsS[l][k] * rowdot[l]) * invn[l];
        lpj[idx] = lpS[l][k] - sp0 * d;
    }

    // LQ[k][v] = sum_l left[l][k]*Qs[l][v]  (old left)
    {
        int v0 = (t & 15) * 4, k0 = (t >> 4) * 2;
        float a[2][4] = {};
        #pragma unroll 4
        for (int l = 0; l < 32; ++l) {
            float e0 = leS[l][k0], e1 = leS[l][k0 + 1];
            float q0 = Qs[l][v0], q1 = Qs[l][v0 + 1], q2 = Qs[l][v0 + 2], q3 = Qs[l][v0 + 3];
            a[0][0] += e0 * q0; a[0][1] += e0 * q1; a[0][2] += e0 * q2; a[0][3] += e0 * q3;
            a[1][0] += e1 * q0; a[1][1] += e1 * q1; a[1][2] += e1 * q2; a[1][3] += e1 * q3;
        }
        float* LQj = LQ + ((size_t)(bh * 64 + j)) * 2048;
        #pragma unroll
        for (int dk = 0; dk < 2; ++dk) {
            float4 val = make_float4(a[dk][0], a[dk][1], a[dk][2], a[dk][3]);
            *reinterpret_cast<float4*>(&LQj[(k0 + dk) * 64 + v0]) = val;
        }
    }
    if (t < 32) {
        float s = 0.f;
        #pragma unroll
        for (int l = 0; l < 32; ++l) { float x = leS[l][t]; s += x * x; }
        l2[(bh * 32 + t) * 64 + j] = s;
    }
}

// Right-factor kernel: one block per (bh, k).
// Computes t2r from (LQ, K), dr, updates rp, then produces KR/r2 for the next
// step from the UPDATED rp.  At STEP==3 it produces Y = right_final * X into
// the KR buffer instead.
template <int STEP>
__global__ __launch_bounds__(256) void kCA(const float* __restrict__ key,
                                           const float* __restrict__ value,
                                           const float* __restrict__ step_size,
                                           float* __restrict__ rp,
                                           const float* __restrict__ LQ,
                                           const float* __restrict__ l2,
                                           float* __restrict__ KR,
                                           float* __restrict__ r2) {
    int blk = blockIdx.x; int bh = blk >> 5; int k = blk & 31;
    int h = bh % NH_;
    int t = threadIdx.x;
    __shared__ float rpS[64][65];
    __shared__ float kS[64][65];    // K[i][v]
    __shared__ float lqS[64][65];   // LQ[j][v]; reused as drS / right'
    __shared__ float invn[64], innew[64], dotS[64], l2S[64];

    float sp1 = softplus_f(step_size[h * 8 + 4 + STEP]);   // [h][1][STEP]
    float* rpk = rp + ((size_t)(bh * 32 + k)) * 4096;
    for (int idx = t; idx < 4096; idx += 256) {
        int r = idx >> 6, c = idx & 63;
        rpS[r][c] = rpk[idx];
        kS[r][c]  = key[((size_t)bh * SS_ + k * 64 + r) * 64 + c];
        lqS[r][c] = LQ[((size_t)(bh * 64 + r) * 32 + k) * 64 + c];
    }
    if (t < 64) l2S[t] = l2[(bh * 32 + k) * 64 + t];
    __syncthreads();
    if (t < 64) {
        float s = 0.f;
        #pragma unroll 8
        for (int i = 0; i < 64; ++i) { float x = rpS[t][i]; s += x * x; }
        float n = sqrtf(s);
        invn[t] = (n > 0.f) ? 1.0f / n : 0.f;
    }
    __syncthreads();

    // t2r[j][i] = sum_v lqS[j][v]*kS[i][v]   (4x4 register blocking)
    {
        int i0 = (t & 15) * 4, j0 = (t >> 4) * 4;
        float acc[4][4] = {};
        #pragma unroll 4
        for (int v = 0; v < 64; ++v) {
            float kv[4], lv[4];
            #pragma unroll
            for (int d = 0; d < 4; ++d) kv[d] = kS[i0 + d][v];
            #pragma unroll
            for (int d = 0; d < 4; ++d) lv[d] = lqS[j0 + d][v];
            #pragma unroll
            for (int a = 0; a < 4; ++a)
                #pragma unroll
                for (int b = 0; b < 4; ++b) acc[a][b] += lv[a] * kv[b];
        }
        __syncthreads();   // all reads of lqS complete; reuse it as drS
        #pragma unroll
        for (int a = 0; a < 4; ++a)
            #pragma unroll
            for (int b = 0; b < 4; ++b) lqS[j0 + a][i0 + b] = acc[a][b];
    }
    __syncthreads();
    // dr1 = 2*rs*(l2[j]*right - t2r)
    for (int idx = t; idx < 4096; idx += 256) {
        int jj = idx >> 6, i = idx & 63;
        float rs = rpS[jj][i] * invn[jj];
        lqS[jj][i] = 2.f * rs * (l2S[jj] * rs * rs - lqS[jj][i]);
    }
    __syncthreads();
    if (t < 64) {
        float s = 0.f;
        #pragma unroll 8
        for (int i = 0; i < 64; ++i) s += (rpS[t][i] * invn[t]) * lqS[t][i];
        dotS[t] = s;
    }
    __syncthreads();
    for (int idx = t; idx < 4096; idx += 256) {
        int jj = idx >> 6, i = idx & 63;
        float rs = rpS[jj][i] * invn[jj];
        float d = (lqS[jj][i] - rs * dotS[jj]) * invn[jj];
        float nrp = rpS[jj][i] - sp1 * d;
        rpS[jj][i] = nrp;
        rpk[idx] = nrp;
    }
    __syncthreads();
    // new norms; r2 = inn^4 * sum(rp^4)
    if (t < 64) {
        float s2 = 0.f, s4 = 0.f;
        #pragma unroll 8
        for (int i = 0; i < 64; ++i) {
            float x = rpS[t][i]; float x2 = x * x; s2 += x2; s4 += x2 * x2;
        }
        float n = sqrtf(s2);
        float inn = (n > 0.f) ? 1.0f / n : 0.f;
        innew[t] = inn;
        if (STEP < 3) {
            float i2 = inn * inn;
            r2[(bh * 64 + t) * 32 + k] = i2 * i2 * s4;
        }
    }
    __syncthreads();
    // right' into lqS
    for (int idx = t; idx < 4096; idx += 256) {
        int jj = idx >> 6, i = idx & 63;
        float rs = rpS[jj][i] * innew[jj];
        lqS[jj][i] = rs * rs;
    }
    if (STEP == 3) {  // load X over kS for the Y contraction
        for (int idx = t; idx < 4096; idx += 256) {
            int r = idx >> 6, c = idx & 63;
            kS[r][c] = value[((size_t)bh * SS_ + k * 64 + r) * 64 + c];
        }
    }
    __syncthreads();
    // KR[j][v] = sum_i right'[j][i]*kS[i][v]   (Y at STEP==3)
    {
        int v0 = (t & 15) * 4, j0 = (t >> 4) * 4;
        float acc[4][4] = {};
        #pragma unroll 4
        for (int i = 0; i < 64; ++i) {
            float kv[4], rg[4];
            #pragma unroll
            for (int d = 0; d < 4; ++d) kv[d] = kS[i][v0 + d];
            #pragma unroll
            for (int d = 0; d < 4; ++d) rg[d] = lqS[j0 + d][i];
            #pragma unroll
            for (int a = 0; a < 4; ++a)
                #pragma unroll
                for (int b = 0; b < 4; ++b) acc[a][b] += rg[a] * kv[b];
        }
        float* KRk = KR + ((size_t)(bh * 32 + k)) * 4096;
        #pragma unroll
        for (int a = 0; a < 4; ++a) {
            float4 val = make_float4(acc[a][0], acc[a][1], acc[a][2], acc[a][3]);
            *reinterpret_cast<float4*>(&KRk[(j0 + a) * 64 + v0]) = val;
        }
    }
}

// Output kernel: one block per (bh, j).  left_final from lp; Z = left @ Y.
// Y may alias out (see layout comment): all Y reads complete into LDS before
// any out write in this block, and other blocks touch disjoint rows.
__global__ __launch_bounds__(256) void kZ(const float* __restrict__ lp,
                                          const float* Y,
                                          float* out) {
    int blk = blockIdx.x; int bh = blk >> 6; int j = blk & 63;
    int t = threadIdx.x;
    __shared__ float Ys[32][65];
    __shared__ float lpS[32][33];
    __shared__ float leS[32][33];
    __shared__ float invn[32];
    for (int idx = t; idx < 2048; idx += 256) {
        int kk = idx >> 6, v = idx & 63;
        Ys[kk][v] = Y[((size_t)(bh * 32 + kk) * 64 + j) * 64 + v];
    }
    const float* lpj = lp + ((size_t)(bh * 64 + j)) * 1024;
    for (int idx = t; idx < 1024; idx += 256) {
        int l = idx >> 5, k = idx & 31;
        lpS[l][k] = lpj[idx];
    }
    __syncthreads();
    if (t < 32) {
        float s = 0.f;
        #pragma unroll
        for (int k = 0; k < 32; ++k) { float x = lpS[t][k]; s += x * x; }
        float n = sqrtf(s);
        invn[t] = (n > 0.f) ? 1.0f / n : 0.f;
    }
    __syncthreads();
    for (int idx = t; idx < 1024; idx += 256) {
        int l = idx >> 5, k = idx & 31;
        float v = lpS[l][k] * invn[l];
        leS[l][k] = v * v;
    }
    __syncthreads();
    {
        int v0 = (t & 15) * 4, l0 = (t >> 4) * 2;
        float a[2][4] = {};
        #pragma unroll 4
        for (int kk = 0; kk < 32; ++kk) {
            float y0 = Ys[kk][v0], y1 = Ys[kk][v0 + 1], y2 = Ys[kk][v0 + 2], y3 = Ys[kk][v0 + 3];
            float e0 = leS[l0][kk], e1 = leS[l0 + 1][kk];
            a[0][0] += e0 * y0; a[0][1] += e0 * y1; a[0][2] += e0 * y2; a[0][3] += e0 * y3;
            a[1][0] += e1 * y0; a[1][1] += e1 * y1; a[1][2] += e1 * y2; a[1][3] += e1 * y3;
        }
        #pragma unroll
        for (int dl = 0; dl < 2; ++dl) {
            float4 val = make_float4(a[dl][0], a[dl][1], a[dl][2], a[dl][3]);
            *reinterpret_cast<float4*>(&out[((size_t)bh * SS_ + (l0 + dl) * 64 + j) * 64 + v0]) = val;
        }
    }
}

extern "C" void kernel_launch(void* const* d_in, const int* in_sizes, int n_in,
                              void* d_out, int out_size, void* d_ws, size_t ws_size,
                              hipStream_t stream) {
    const float* query = (const float*)d_in[0];
    const float* key   = (const float*)d_in[1];
    const float* value = (const float*)d_in[2];
    const float* attn  = (const float*)d_in[3];
    const float* ss    = (const float*)d_in[4];
    float* out = (float*)d_out;

    // Workspace budget (floats):
    const size_t n_lp = (size_t)BH_ * 64 * 32 * 32;   // 3,145,728
    const size_t n_rp = (size_t)BH_ * 32 * 64 * 64;   // 6,291,456
    const size_t n_LQ = (size_t)BH_ * 64 * 32 * 64;   // 6,291,456
    const size_t n_r2 = (size_t)BH_ * 64 * 32;        //    98,304
    const size_t n_l2 = (size_t)BH_ * 32 * 64;        //    98,304
    const size_t need = (n_lp + n_rp + n_LQ + n_r2 + n_l2) * sizeof(float); // ~63.7 MB
    if (ws_size < need) return;  // graceful fail (wrong output) instead of OOB crash

    float* ws = (float*)d_ws;
    float* lp = ws;
    float* rp = lp + n_lp;
    float* LQ = rp + n_rp;
    float* r2 = LQ + n_LQ;
    float* l2 = r2 + n_r2;
    float* KR = out;   // KR / Y buffer aliased onto d_out (25.2 MB saved)

    dim3 blkD(256);
    const int gK = BH_ * 32;   // 1536 blocks (per bh,k)
    const int gJ = BH_ * 64;   // 3072 blocks (per bh,j)

    kA0<<<gK, blkD, 0, stream>>>(key, rp, KR, r2);
    kB<0><<<gJ, blkD, 0, stream>>>(query, attn, ss, lp, KR, r2, LQ, l2);
    kCA<0><<<gK, blkD, 0, stream>>>(key, value, ss, rp, LQ, l2, KR, r2);
    kB<1><<<gJ, blkD, 0, stream>>>(query, attn, ss, lp, KR, r2, LQ, l2);
    kCA<1><<<gK, blkD, 0, stream>>>(key, value, ss, rp, LQ, l2, KR, r2);
    kB<2><<<gJ, blkD, 0, stream>>>(query, attn, ss, lp, KR, r2, LQ, l2);
    kCA<2><<<gK, blkD, 0, stream>>>(key, value, ss, rp, LQ, l2, KR, r2);
    kB<3><<<gJ, blkD, 0, stream>>>(query, attn, ss, lp, KR, r2, LQ, l2);
    kCA<3><<<gK, blkD, 0, stream>>>(key, value, ss, rp, LQ, l2, KR, r2);  // emits Y
    kZ<<<gJ, blkD, 0, stream>>>(lp, KR, out);
}

// Round 4
// 376.918 us; speedup vs baseline: 1.3784x; 1.3784x over previous
//
#include <hip/hip_runtime.h>
#include <cmath>

// Problem constants (B=4, H=12, S=2048, D=64, BLOCK=64, L=32, NUM_STEPS=4)
#define BH_ 48
#define NH_ 12
#define SS_ 2048

__device__ __forceinline__ float softplus_f(float x) {
    return fmaxf(x, 0.0f) + log1pf(expf(-fabsf(x)));
}

// ---------------------------------------------------------------------------
// Buffers (float32):
//   lp  : [BH][64(j)][32(l)][32(k)]      ws
//   rp  : [BH][32(k)][64(j)][64(i)]      ws
//   LQ  : [BH][64(j)][32(k)][64(v)]      ws
//   r2  : [BH][64(j)][32(k)]             ws   (also holds K-block means for kB<0>)
//   l2  : [BH][32(k)][64(j)]             ws
//   KR  : [BH][32(k)][64(j)][64(v)]      ALIASED ONTO d_out (also Y)
// KR<->out aliasing race-free: only kZ reads Y while writing out; block (bh,j)
// loads exactly the rows it later writes (same flat set), others disjoint.
// ---------------------------------------------------------------------------

// kA0-lite: per (bh,k) column means of the K block (= KR at step 0, since
// right_0 is uniform 1/64).  Written into the r2 buffer (free until kCA<0>).
__global__ __launch_bounds__(64) void kA0(const float* __restrict__ key,
                                          float* __restrict__ mean) {
    int blk = blockIdx.x; int bh = blk >> 5; int k = blk & 31;
    int t = threadIdx.x;
    const float* kb = key + ((size_t)bh * SS_ + k * 64) * 64;
    float acc = 0.f;
    #pragma unroll
    for (int i = 0; i < 64; ++i) acc += kb[i * 64 + t];
    mean[((size_t)bh * 32 + k) * 64 + t] = acc * (1.0f / 64.0f);
}

// kB: one block per (bh,j).  lp owned in registers (8 lanes/row, 4 cols each).
// t2l and LQ matmuls fully float4-vectorized from LDS.
template <int STEP>
__global__ __launch_bounds__(256) void kB(const float* __restrict__ query,
                                          const float* __restrict__ attn_scale,
                                          const float* __restrict__ step_size,
                                          float* __restrict__ lp,
                                          const float* __restrict__ KR,  // mean at STEP==0
                                          const float* __restrict__ r2,
                                          float* __restrict__ LQ,
                                          float* __restrict__ l2) {
    int blk = blockIdx.x; int bh = blk >> 6; int j = blk & 63;
    int h = bh % NH_; int t = threadIdx.x;
    __shared__ float Qs[32][68];    // 32 rows x 64 v-cols, stride 68 (2-way = free)
    __shared__ float KRs[32][68];
    __shared__ float leS[32][33];
    __shared__ float t2S[32][33];

    float qscale = softplus_f(attn_scale[h]) * 0.125f;
    float sp0 = softplus_f(step_size[h * 8 + STEP]);

    for (int idx = t; idx < 512; idx += 256) {
        int r = idx >> 4, c4 = (idx & 15) * 4;
        float4 q = *(const float4*)&query[((size_t)bh * SS_ + r * 64 + j) * 64 + c4];
        q.x *= qscale; q.y *= qscale; q.z *= qscale; q.w *= qscale;
        *(float4*)&Qs[r][c4] = q;
        float4 kr;
        if (STEP == 0) kr = *(const float4*)&KR[((size_t)bh * 32 + r) * 64 + c4];
        else           kr = *(const float4*)&KR[((size_t)(bh * 32 + r) * 64 + j) * 64 + c4];
        *(float4*)&KRs[r][c4] = kr;
    }

    // owner mapping: row lo = t>>3 (l), cols c0..c0+3 (k)
    int lo = t >> 3, c0 = (t & 7) * 4;
    float lpv[4], r2v[4];
    if (STEP == 0) {
        #pragma unroll
        for (int d = 0; d < 4; ++d) { lpv[d] = 0.17677669529663687f; r2v[d] = 1.0f / 64.0f; }
    } else {
        float4 v = *(const float4*)&lp[((size_t)(bh * 64 + j)) * 1024 + lo * 32 + c0];
        lpv[0] = v.x; lpv[1] = v.y; lpv[2] = v.z; lpv[3] = v.w;
        float4 w = *(const float4*)&r2[((size_t)(bh * 64 + j)) * 32 + c0];
        r2v[0] = w.x; r2v[1] = w.y; r2v[2] = w.z; r2v[3] = w.w;
    }
    float s = lpv[0]*lpv[0] + lpv[1]*lpv[1] + lpv[2]*lpv[2] + lpv[3]*lpv[3];
    s += __shfl_xor(s, 1); s += __shfl_xor(s, 2); s += __shfl_xor(s, 4);
    float n = sqrtf(s);
    float invn = (n > 0.f) ? 1.0f / n : 0.f;
    float ls[4], le[4];
    #pragma unroll
    for (int d = 0; d < 4; ++d) {
        ls[d] = lpv[d] * invn; le[d] = ls[d] * ls[d];
        leS[lo][c0 + d] = le[d];
    }
    __syncthreads();

    // t2l[l][k] = sum_v Qs[l][v]*KRs[k][v]  (2x2 block-cyclic, float4 over v)
    {
        int ml = t >> 4, mk = t & 15;
        float a00 = 0, a01 = 0, a10 = 0, a11 = 0;
        #pragma unroll 4
        for (int v4 = 0; v4 < 16; ++v4) {
            float4 q0 = *(const float4*)&Qs[ml][v4 * 4];
            float4 q1 = *(const float4*)&Qs[ml + 16][v4 * 4];
            float4 r0 = *(const float4*)&KRs[mk][v4 * 4];
            float4 r1 = *(const float4*)&KRs[mk + 16][v4 * 4];
            a00 += q0.x*r0.x + q0.y*r0.y + q0.z*r0.z + q0.w*r0.w;
            a01 += q0.x*r1.x + q0.y*r1.y + q0.z*r1.z + q0.w*r1.w;
            a10 += q1.x*r0.x + q1.y*r0.y + q1.z*r0.z + q1.w*r0.w;
            a11 += q1.x*r1.x + q1.y*r1.y + q1.z*r1.z + q1.w*r1.w;
        }
        t2S[ml][mk] = a00; t2S[ml][mk + 16] = a01;
        t2S[ml + 16][mk] = a10; t2S[ml + 16][mk + 16] = a11;
    }
    __syncthreads();

    // owner: dl, project, update lp
    {
        float dl[4]; float rd = 0.f;
        #pragma unroll
        for (int d = 0; d < 4; ++d) {
            float t2 = t2S[lo][c0 + d];
            dl[d] = 2.f * ls[d] * (r2v[d] * le[d] - t2);
            rd += ls[d] * dl[d];
        }
        rd += __shfl_xor(rd, 1); rd += __shfl_xor(rd, 2); rd += __shfl_xor(rd, 4);
        float4 outv;
        outv.x = lpv[0] - sp0 * ((dl[0] - ls[0] * rd) * invn);
        outv.y = lpv[1] - sp0 * ((dl[1] - ls[1] * rd) * invn);
        outv.z = lpv[2] - sp0 * ((dl[2] - ls[2] * rd) * invn);
        outv.w = lpv[3] - sp0 * ((dl[3] - ls[3] * rd) * invn);
        *(float4*)&lp[((size_t)(bh * 64 + j)) * 1024 + lo * 32 + c0] = outv;
    }

    // LQ[k][v] = sum_l le[l][k]*Qs[l][v]  (old left)
    {
        int mk = t >> 4, v0 = (t & 15) * 4;
        float4 b0 = {0, 0, 0, 0}, b1 = {0, 0, 0, 0};
        #pragma unroll 4
        for (int l = 0; l < 32; ++l) {
            float e0 = leS[l][mk], e1 = leS[l][mk + 16];
            float4 q = *(const float4*)&Qs[l][v0];
            b0.x += e0 * q.x; b0.y += e0 * q.y; b0.z += e0 * q.z; b0.w += e0 * q.w;
            b1.x += e1 * q.x; b1.y += e1 * q.y; b1.z += e1 * q.z; b1.w += e1 * q.w;
        }
        float* LQj = LQ + ((size_t)(bh * 64 + j)) * 2048;
        *(float4*)&LQj[mk * 64 + v0] = b0;
        *(float4*)&LQj[(mk + 16) * 64 + v0] = b1;
    }

    // l2[k] = sum_l le[l][k]^2  (one wave)
    if (t < 64) {
        int k = t & 31, hh = t >> 5;
        float s2 = 0.f;
        #pragma unroll
        for (int l = hh * 16; l < hh * 16 + 16; ++l) { float x = leS[l][k]; s2 += x * x; }
        s2 += __shfl_xor(s2, 32);
        if (hh == 0) l2[(bh * 32 + k) * 64 + j] = s2;
    }
}

// kCA: one block per (bh,k).  rp owned in registers (4 lanes/row, 16 cols).
// LDS only holds kS and lqS (reused as t2rS then rightS).
template <int STEP>
__global__ __launch_bounds__(256) void kCA(const float* __restrict__ key,
                                           const float* __restrict__ value,
                                           const float* __restrict__ step_size,
                                           float* __restrict__ rp,
                                           const float* __restrict__ LQ,
                                           const float* __restrict__ l2,
                                           float* __restrict__ KR,
                                           float* __restrict__ r2) {
    int blk = blockIdx.x; int bh = blk >> 5; int k = blk & 31;
    int h = bh % NH_; int t = threadIdx.x;
    __shared__ float kS[64][68];
    __shared__ float lqS[64][68];   // LQ -> t2rS -> rightS
    __shared__ float l2S[64];

    float sp1 = softplus_f(step_size[h * 8 + 4 + STEP]);
    float* rpk = rp + ((size_t)(bh * 32 + k)) * 4096;

    for (int idx = t; idx < 1024; idx += 256) {
        int r = idx >> 4, c4 = (idx & 15) * 4;
        *(float4*)&kS[r][c4]  = *(const float4*)&key[((size_t)bh * SS_ + k * 64 + r) * 64 + c4];
        *(float4*)&lqS[r][c4] = *(const float4*)&LQ[((size_t)(bh * 64 + r) * 32 + k) * 64 + c4];
    }
    if (t < 64) l2S[t] = l2[(bh * 32 + k) * 64 + t];

    int jo = t >> 2, c0 = (t & 3) * 16;
    float rv[16];
    if (STEP == 0) {
        #pragma unroll
        for (int i = 0; i < 16; ++i) rv[i] = 0.125f;
    } else {
        #pragma unroll
        for (int q4 = 0; q4 < 4; ++q4) {
            float4 v = *(const float4*)&rpk[jo * 64 + c0 + q4 * 4];
            rv[q4 * 4] = v.x; rv[q4 * 4 + 1] = v.y; rv[q4 * 4 + 2] = v.z; rv[q4 * 4 + 3] = v.w;
        }
    }
    float s2 = 0.f;
    #pragma unroll
    for (int i = 0; i < 16; ++i) s2 += rv[i] * rv[i];
    s2 += __shfl_xor(s2, 1); s2 += __shfl_xor(s2, 2);
    float n = sqrtf(s2);
    float invn = (n > 0.f) ? 1.0f / n : 0.f;
    __syncthreads();

    // t2r[j][i] = sum_v lqS[j][v]*kS[i][v]  (4x4 block-cyclic, float4 over v)
    int mi = t & 15, mj = t >> 4;
    float acc[4][4] = {};
    #pragma unroll 2
    for (int v4 = 0; v4 < 16; ++v4) {
        float4 lq[4], kk[4];
        #pragma unroll
        for (int d = 0; d < 4; ++d) lq[d] = *(const float4*)&lqS[mj + 16 * d][v4 * 4];
        #pragma unroll
        for (int d = 0; d < 4; ++d) kk[d] = *(const float4*)&kS[mi + 16 * d][v4 * 4];
        #pragma unroll
        for (int a = 0; a < 4; ++a)
            #pragma unroll
            for (int b = 0; b < 4; ++b)
                acc[a][b] += lq[a].x * kk[b].x + lq[a].y * kk[b].y +
                             lq[a].z * kk[b].z + lq[a].w * kk[b].w;
    }
    __syncthreads();
    #pragma unroll
    for (int a = 0; a < 4; ++a)
        #pragma unroll
        for (int b = 0; b < 4; ++b) lqS[mj + 16 * a][mi + 16 * b] = acc[a][b];
    if (STEP == 3) {   // X over kS (t2r's kS reads finished at prior sync)
        for (int idx = t; idx < 1024; idx += 256) {
            int r = idx >> 4, c4 = (idx & 15) * 4;
            *(float4*)&kS[r][c4] = *(const float4*)&value[((size_t)bh * SS_ + k * 64 + r) * 64 + c4];
        }
    }
    __syncthreads();

    // owner: dr, project, update rp, new norms
    float dv[16];
    #pragma unroll
    for (int q4 = 0; q4 < 4; ++q4) {
        float4 v = *(const float4*)&lqS[jo][c0 + q4 * 4];
        dv[q4 * 4] = v.x; dv[q4 * 4 + 1] = v.y; dv[q4 * 4 + 2] = v.z; dv[q4 * 4 + 3] = v.w;
    }
    float l2j = l2S[jo];
    float dot = 0.f;
    #pragma unroll
    for (int i = 0; i < 16; ++i) {
        float rs = rv[i] * invn;
        dv[i] = 2.f * rs * (l2j * rs * rs - dv[i]);
        dot += rs * dv[i];
    }
    dot += __shfl_xor(dot, 1); dot += __shfl_xor(dot, 2);
    float s2n = 0.f, s4n = 0.f;
    #pragma unroll
    for (int i = 0; i < 16; ++i) {
        float rs = rv[i] * invn;
        float d = (dv[i] - rs * dot) * invn;
        rv[i] -= sp1 * d;
        float x2 = rv[i] * rv[i];
        s2n += x2; s4n += x2 * x2;
    }
    s2n += __shfl_xor(s2n, 1); s2n += __shfl_xor(s2n, 2);
    s4n += __shfl_xor(s4n, 1); s4n += __shfl_xor(s4n, 2);
    float nn = sqrtf(s2n);
    float inn = (nn > 0.f) ? 1.0f / nn : 0.f;
    if (STEP < 3) {
        #pragma unroll
        for (int q4 = 0; q4 < 4; ++q4) {
            float4 v = make_float4(rv[q4*4], rv[q4*4+1], rv[q4*4+2], rv[q4*4+3]);
            *(float4*)&rpk[jo * 64 + c0 + q4 * 4] = v;
        }
        if ((t & 3) == 0) {
            float i2 = inn * inn;
            r2[(bh * 64 + jo) * 32 + k] = i2 * i2 * s4n;
        }
    }
    __syncthreads();   // owners finished reading t2rS

    // right' into lqS
    #pragma unroll
    for (int q4 = 0; q4 < 4; ++q4) {
        float4 w;
        float a0 = rv[q4*4] * inn, a1 = rv[q4*4+1] * inn, a2 = rv[q4*4+2] * inn, a3 = rv[q4*4+3] * inn;
        w.x = a0 * a0; w.y = a1 * a1; w.z = a2 * a2; w.w = a3 * a3;
        *(float4*)&lqS[jo][c0 + q4 * 4] = w;
    }
    __syncthreads();

    // KR[j][v] = sum_i right'[j][i]*kS[i][v]   (Y at STEP==3)
    {
        float4 oc[4] = {{0,0,0,0}, {0,0,0,0}, {0,0,0,0}, {0,0,0,0}};
        int v0 = mi * 4;
        #pragma unroll 2
        for (int i4 = 0; i4 < 16; ++i4) {
            float4 k0 = *(const float4*)&kS[i4 * 4 + 0][v0];
            float4 k1 = *(const float4*)&kS[i4 * 4 + 1][v0];
            float4 k2 = *(const float4*)&kS[i4 * 4 + 2][v0];
            float4 k3 = *(const float4*)&kS[i4 * 4 + 3][v0];
            #pragma unroll
            for (int a = 0; a < 4; ++a) {
                float4 rg = *(const float4*)&lqS[mj + 16 * a][i4 * 4];
                oc[a].x += rg.x * k0.x + rg.y * k1.x + rg.z * k2.x + rg.w * k3.x;
                oc[a].y += rg.x * k0.y + rg.y * k1.y + rg.z * k2.y + rg.w * k3.y;
                oc[a].z += rg.x * k0.z + rg.y * k1.z + rg.z * k2.z + rg.w * k3.z;
                oc[a].w += rg.x * k0.w + rg.y * k1.w + rg.z * k2.w + rg.w * k3.w;
            }
        }
        float* KRk = KR + ((size_t)(bh * 32 + k)) * 4096;
        #pragma unroll
        for (int a = 0; a < 4; ++a)
            *(float4*)&KRk[(mj + 16 * a) * 64 + v0] = oc[a];
    }
}

// kZ: one block per (bh,j).  Z[l][v] = sum_k left[l][k]*Y[k][v].
__global__ __launch_bounds__(256) void kZ(const float* __restrict__ lp,
                                          const float* Y,
                                          float* out) {
    int blk = blockIdx.x; int bh = blk >> 6; int j = blk & 63;
    int t = threadIdx.x;
    __shared__ float Ys[32][68];
    __shared__ float leS[32][33];

    for (int idx = t; idx < 512; idx += 256) {
        int r = idx >> 4, c4 = (idx & 15) * 4;
        *(float4*)&Ys[r][c4] = *(const float4*)&Y[((size_t)(bh * 32 + r) * 64 + j) * 64 + c4];
    }
    int lo = t >> 3, c0 = (t & 7) * 4;
    float4 v = *(const float4*)&lp[((size_t)(bh * 64 + j)) * 1024 + lo * 32 + c0];
    float s = v.x*v.x + v.y*v.y + v.z*v.z + v.w*v.w;
    s += __shfl_xor(s, 1); s += __shfl_xor(s, 2); s += __shfl_xor(s, 4);
    float n = sqrtf(s);
    float invn = (n > 0.f) ? 1.0f / n : 0.f;
    float a0 = v.x * invn, a1 = v.y * invn, a2 = v.z * invn, a3 = v.w * invn;
    leS[lo][c0] = a0 * a0; leS[lo][c0 + 1] = a1 * a1;
    leS[lo][c0 + 2] = a2 * a2; leS[lo][c0 + 3] = a3 * a3;
    __syncthreads();

    {
        int ml = t >> 4, v0 = (t & 15) * 4;
        float4 b0 = {0, 0, 0, 0}, b1 = {0, 0, 0, 0};
        #pragma unroll 4
        for (int kk = 0; kk < 32; ++kk) {
            float e0 = leS[ml][kk], e1 = leS[ml + 16][kk];
            float4 y = *(const float4*)&Ys[kk][v0];
            b0.x += e0 * y.x; b0.y += e0 * y.y; b0.z += e0 * y.z; b0.w += e0 * y.w;
            b1.x += e1 * y.x; b1.y += e1 * y.y; b1.z += e1 * y.z; b1.w += e1 * y.w;
        }
        *(float4*)&out[((size_t)bh * SS_ + ml * 64 + j) * 64 + v0] = b0;
        *(float4*)&out[((size_t)bh * SS_ + (ml + 16) * 64 + j) * 64 + v0] = b1;
    }
}

extern "C" void kernel_launch(void* const* d_in, const int* in_sizes, int n_in,
                              void* d_out, int out_size, void* d_ws, size_t ws_size,
                              hipStream_t stream) {
    const float* query = (const float*)d_in[0];
    const float* key   = (const float*)d_in[1];
    const float* value = (const float*)d_in[2];
    const float* attn  = (const float*)d_in[3];
    const float* ss    = (const float*)d_in[4];
    float* out = (float*)d_out;

    const size_t n_lp = (size_t)BH_ * 64 * 32 * 32;   // 3,145,728
    const size_t n_rp = (size_t)BH_ * 32 * 64 * 64;   // 6,291,456
    const size_t n_LQ = (size_t)BH_ * 64 * 32 * 64;   // 6,291,456
    const size_t n_r2 = (size_t)BH_ * 64 * 32;        //    98,304
    const size_t n_l2 = (size_t)BH_ * 32 * 64;        //    98,304
    const size_t need = (n_lp + n_rp + n_LQ + n_r2 + n_l2) * sizeof(float); // ~63.7 MB
    if (ws_size < need) return;

    float* ws = (float*)d_ws;
    float* lp = ws;
    float* rp = lp + n_lp;
    float* LQ = rp + n_rp;
    float* r2 = LQ + n_LQ;
    float* l2 = r2 + n_r2;
    float* KR = out;       // KR / Y aliased onto d_out
    float* mean = r2;      // K-block means live in r2 until kCA<0> writes real r2

    dim3 blkD(256);
    const int gK = BH_ * 32;   // 1536
    const int gJ = BH_ * 64;   // 3072

    kA0<<<gK, dim3(64), 0, stream>>>(key, mean);
    kB<0><<<gJ, blkD, 0, stream>>>(query, attn, ss, lp, mean, r2, LQ, l2);
    kCA<0><<<gK, blkD, 0, stream>>>(key, value, ss, rp, LQ, l2, KR, r2);
    kB<1><<<gJ, blkD, 0, stream>>>(query, attn, ss, lp, KR, r2, LQ, l2);
    kCA<1><<<gK, blkD, 0, stream>>>(key, value, ss, rp, LQ, l2, KR, r2);
    kB<2><<<gJ, blkD, 0, stream>>>(query, attn, ss, lp, KR, r2, LQ, l2);
    kCA<2><<<gK, blkD, 0, stream>>>(key, value, ss, rp, LQ, l2, KR, r2);
    kB<3><<<gJ, blkD, 0, stream>>>(query, attn, ss, lp, KR, r2, LQ, l2);
    kCA<3><<<gK, blkD, 0, stream>>>(key, value, ss, rp, LQ, l2, KR, r2);  // emits Y
    kZ<<<gJ, blkD, 0, stream>>>(lp, KR, out);
}